// Round 4
// baseline (484.061 us; speedup 1.0000x reference)
//
#include <hip/hip_runtime.h>
#include <math.h>

#define BB 256      // batch
#define IC 1152     // in caps
#define OC 10       // out caps
#define OD 16       // out dim
#define ID 8        // in dim
#define ODOC 160

#define K1_CH 72        // i-chunks of 16
#define K1_BG 8         // b residue groups (32 b each)
#define K1_THREADS 320  // 16 il x (10 o x 2 dh)

#define SPLIT 8            // i-split for routing passes
#define SEG_I (IC/SPLIT)   // 144
#define P_THREADS 256      // 16 il x 16 slot
#define P_STEPS (SEG_I/16) // 9

typedef unsigned int   u32;
typedef unsigned short u16;

__device__ __forceinline__ float grp16_sum(float x) {
#pragma unroll
    for (int m = 8; m >= 1; m >>= 1) x += __shfl_xor(x, m, 16);
    return x;
}
__device__ __forceinline__ float grp16_max(float x) {
#pragma unroll
    for (int m = 8; m >= 1; m >>= 1) x = fmaxf(x, __shfl_xor(x, m, 16));
    return x;
}
// squash over the 16-lane d-group
__device__ __forceinline__ float squash_val(float s) {
    float sq = grp16_sum(s * s);
    return s * (sq / ((1.f + sq) * (sqrtf(sq) + 1e-8f)));
}

__device__ __forceinline__ u32 bf16_rne(float f) {
    u32 x = __float_as_uint(f);
    return (x + 0x7FFFu + ((x >> 16) & 1u)) >> 16;
}
__device__ __forceinline__ u32 pack_bf16x2(float lo, float hi) {
    return bf16_rne(lo) | (bf16_rne(hi) << 16);
}
__device__ __forceinline__ float bf_lo(u32 v) { return __uint_as_float(v << 16); }
__device__ __forceinline__ float bf_hi(u32 v) { return __uint_as_float(v & 0xFFFF0000u); }

// Kernel 1: uhat (bf16) = W @ u, PLUS s0[b,o,d] = sum_i uhat (uniform-c pass 0),
// eliminating one full 94 MB read pass. Thread = (il, o, dh): 8 d's -> uint4
// bf16x8 store. W in regs (64 f/thread) reused over 32 b's. At iter bb all
// blocks write b in {bb*8..bb*8+7}: dense monotone 2.5 MB write window.
// s0: LDS atomic reduce over il, then 160 spread global atomics per iter.
__global__ __launch_bounds__(K1_THREADS, 3) void uhat_kernel(const float* __restrict__ u,
                                                             const float* __restrict__ W,
                                                             u16* __restrict__ uhat,
                                                             float* __restrict__ s0g) {
    __shared__ float us[32][16][ID];      // 16 KB
    __shared__ float s0_blk[32][ODOC];    // 20 KB

    const int t = threadIdx.x;
    const int chunk = blockIdx.x % K1_CH;
    const int bg    = blockIdx.x / K1_CH;
    const int i0 = chunk * 16;

    for (int idx = t; idx < 32 * 16 * ID; idx += K1_THREADS) {
        int bb = idx >> 7, r = idx & 127, il = r >> 3, k = r & 7;
        us[bb][il][k] = u[((size_t)(bb * K1_BG + bg) * IC + i0 + il) * ID + k];
    }
    for (int idx = t; idx < 32 * ODOC; idx += K1_THREADS)
        ((float*)s0_blk)[idx] = 0.f;
    __syncthreads();

    const int il = t / 20;
    const int r  = t % 20;
    const int o  = r >> 1;
    const int dh = r & 1;
    const int i  = i0 + il;

    float w[8][ID];
    const float* wp = W + (((size_t)i * OC + o) * OD + dh * 8) * ID;
#pragma unroll
    for (int j = 0; j < 8; j++)
#pragma unroll
        for (int k = 0; k < ID; k++) w[j][k] = wp[j * ID + k];

    for (int bb = 0; bb < 32; ++bb) {
        const int b = bb * K1_BG + bg;
        float acc[8];
#pragma unroll
        for (int j = 0; j < 8; j++) acc[j] = 0.f;
#pragma unroll
        for (int k = 0; k < ID; k++) {
            float uu = us[bb][il][k];
#pragma unroll
            for (int j = 0; j < 8; j++) acc[j] += w[j][k] * uu;
        }
        uint4 pk;
        pk.x = pack_bf16x2(acc[0], acc[1]);
        pk.y = pack_bf16x2(acc[2], acc[3]);
        pk.z = pack_bf16x2(acc[4], acc[5]);
        pk.w = pack_bf16x2(acc[6], acc[7]);
        *(uint4*)(uhat + ((size_t)b * IC + i) * ODOC + o * OD + dh * 8) = pk;
#pragma unroll
        for (int j = 0; j < 8; j++)
            atomicAdd(&s0_blk[bb][o * OD + dh * 8 + j], acc[j]);
        __syncthreads();
        if (t < ODOC) atomicAdd(&s0g[(size_t)b * ODOC + t], s0_blk[bb][t]);
    }
}

// Pass kernel: L is LINEAR in past v's (L_t = uh . sum_{tau<t} v_tau), so each
// pass is stateless: agreement vector = v0 (pass 1) or v0+v1 (pass 2). i split
// 8-way across blocks -> 2048 blocks; partial s via 160 atomics/block. Pass 2:
// last-arriving block per b (done counter) squashes s2 and writes out.
template <int PASS>
__global__ __launch_bounds__(P_THREADS, 4) void pass_kernel(const u16* __restrict__ uhat,
                                                            const float* __restrict__ s0g,
                                                            const float* __restrict__ s1g,
                                                            float* __restrict__ sout,
                                                            u32* __restrict__ done,
                                                            float* __restrict__ out) {
    __shared__ float v_sh[ODOC];
    __shared__ float red[16 * ODOC];   // 10 KB
    __shared__ u32 flag;

    const int t   = threadIdx.x;
    const int b   = blockIdx.x >> 3;
    const int seg = blockIdx.x & 7;
    const int il   = t >> 4;
    const int slot = t & 15;
    const bool act = slot < OC;

    if (t < ODOC) {
        float wv = squash_val(s0g[(size_t)b * ODOC + t] * 0.1f);   // v0
        if (PASS == 2) wv += squash_val(s1g[(size_t)b * ODOC + t]); // + v1
        v_sh[t] = wv;
    }
    __syncthreads();

    float vr[OD];
#pragma unroll
    for (int q = 0; q < 4; q++) {
        float4 vq = *(const float4*)&v_sh[slot * OD + q * 4];
        vr[q * 4 + 0] = vq.x; vr[q * 4 + 1] = vq.y;
        vr[q * 4 + 2] = vq.z; vr[q * 4 + 3] = vq.w;
    }
    float sp[OD];
#pragma unroll
    for (int d = 0; d < OD; d++) sp[d] = 0.f;

    const u16* ub = uhat + (size_t)b * IC * ODOC;

#pragma unroll
    for (int step = 0; step < P_STEPS; ++step) {
        const int i = seg * SEG_I + step * 16 + il;
        float uh[OD];
        float a = 0.f;
        if (act) {
            const uint4* p = (const uint4*)(ub + (size_t)i * ODOC + slot * OD);
            uint4 A = p[0], B = p[1];
            uh[0]  = bf_lo(A.x); uh[1]  = bf_hi(A.x);
            uh[2]  = bf_lo(A.y); uh[3]  = bf_hi(A.y);
            uh[4]  = bf_lo(A.z); uh[5]  = bf_hi(A.z);
            uh[6]  = bf_lo(A.w); uh[7]  = bf_hi(A.w);
            uh[8]  = bf_lo(B.x); uh[9]  = bf_hi(B.x);
            uh[10] = bf_lo(B.y); uh[11] = bf_hi(B.y);
            uh[12] = bf_lo(B.z); uh[13] = bf_hi(B.z);
            uh[14] = bf_lo(B.w); uh[15] = bf_hi(B.w);
#pragma unroll
            for (int d = 0; d < OD; d++) a += uh[d] * vr[d];
        }
        float Lv = act ? a : -3.4e38f;
        float mx = grp16_max(Lv);
        float e  = act ? __expf(Lv - mx) : 0.f;
        float S  = grp16_sum(e);
        float c  = e / S;
        if (act) {
#pragma unroll
            for (int d = 0; d < OD; d++) sp[d] += c * uh[d];
        }
    }

    if (act) {
#pragma unroll
        for (int q = 0; q < 4; q++)
            *(float4*)&red[il * ODOC + slot * OD + q * 4] =
                make_float4(sp[q * 4], sp[q * 4 + 1], sp[q * 4 + 2], sp[q * 4 + 3]);
    }
    __syncthreads();
    if (t < ODOC) {
        float sn = 0.f;
#pragma unroll
        for (int j = 0; j < 16; j++) sn += red[j * ODOC + t];
        atomicAdd(&sout[(size_t)b * ODOC + t], sn);
    }

    if (PASS == 2) {
        __syncthreads();   // compiler drains vmcnt before barrier -> our atomics done
        if (t == 0) {
            __threadfence();
            flag = atomicAdd(&done[b], 1u);
        }
        __syncthreads();
        if (flag == SPLIT - 1) {
            __threadfence();
            if (t < ODOC) {
                // atomic-read for coherence across XCDs
                float sv = atomicAdd(&sout[(size_t)b * ODOC + t], 0.f);
                float vv = squash_val(sv);
                out[(size_t)b * ODOC + t] = vv;
            }
        }
    }
}

extern "C" void kernel_launch(void* const* d_in, const int* in_sizes, int n_in,
                              void* d_out, int out_size, void* d_ws, size_t ws_size,
                              hipStream_t stream) {
    const float* u = (const float*)d_in[0];
    const float* W = (const float*)d_in[1];
    float* out = (float*)d_out;

    const size_t uhat_bytes = (size_t)BB * IC * ODOC * sizeof(u16);   // 94,371,840
    u16*   uhat = (u16*)d_ws;
    float* s0g  = (float*)((char*)d_ws + uhat_bytes);
    float* s1g  = s0g + (size_t)BB * ODOC;
    float* s2g  = s1g + (size_t)BB * ODOC;
    u32*   done = (u32*)(s2g + (size_t)BB * ODOC);

    // zero s0, s1, s2, done in one shot (contiguous)
    hipMemsetAsync(s0g, 0, (size_t)3 * BB * ODOC * sizeof(float) + BB * sizeof(u32), stream);

    hipLaunchKernelGGL(uhat_kernel, dim3(K1_CH * K1_BG), dim3(K1_THREADS), 0, stream,
                       u, W, uhat, s0g);
    hipLaunchKernelGGL((pass_kernel<1>), dim3(BB * SPLIT), dim3(P_THREADS), 0, stream,
                       uhat, s0g, (const float*)nullptr, s1g, done, out);
    hipLaunchKernelGGL((pass_kernel<2>), dim3(BB * SPLIT), dim3(P_THREADS), 0, stream,
                       uhat, s0g, s1g, s2g, done, out);
}

// Round 5
// 323.633 us; speedup vs baseline: 1.4957x; 1.4957x over previous
//
#include <hip/hip_runtime.h>
#include <math.h>

#define BB 256      // batch
#define IC 1152     // in caps
#define OC 10       // out caps
#define OD 16       // out dim
#define ID 8        // in dim
#define ODOC 160

#define NCHUNK 144      // i-chunks of 8
#define NBG 8           // b residue groups (32 b each)
#define UK_THREADS 320  // 8 il x 40 (o,dq)

#define R_THREADS 1024  // 64 il x 16 slot
#define R_STEPS (IC/64) // 18

typedef unsigned int   u32;
typedef unsigned short u16;

__device__ __forceinline__ float grp16_sum(float x) {
#pragma unroll
    for (int m = 8; m >= 1; m >>= 1) x += __shfl_xor(x, m, 16);
    return x;
}
__device__ __forceinline__ float grp16_max(float x) {
#pragma unroll
    for (int m = 8; m >= 1; m >>= 1) x = fmaxf(x, __shfl_xor(x, m, 16));
    return x;
}
// squash over the 16-lane d-group
__device__ __forceinline__ float squash_val(float s) {
    float sq = grp16_sum(s * s);
    return s * (sq / ((1.f + sq) * (sqrtf(sq) + 1e-8f)));
}

__device__ __forceinline__ u32 bf16_rne(float f) {
    u32 x = __float_as_uint(f);
    return (x + 0x7FFFu + ((x >> 16) & 1u)) >> 16;
}
__device__ __forceinline__ u32 pack_bf16x2(float lo, float hi) {
    return bf16_rne(lo) | (bf16_rne(hi) << 16);
}
__device__ __forceinline__ float bf_lo(u32 v) { return __uint_as_float(v << 16); }
__device__ __forceinline__ float bf_hi(u32 v) { return __uint_as_float(v & 0xFFFF0000u); }

// Kernel 1 (round-3 structure, proven write-roofline): uhat (bf16) = W @ u.
// ADDED: s0[b,o,d] = sum_i uhat via LDS ds_add_f32 in-loop (NO barriers in the
// bb loop -> store stream keeps flowing) + one global-atomic flush at the end.
// At iter bb all 1152 blocks write b in {8bb..8bb+7}: dense monotone write window.
__global__ __launch_bounds__(UK_THREADS) void uhat_kernel(const float* __restrict__ u,
                                                          const float* __restrict__ W,
                                                          u16* __restrict__ uhat,
                                                          float* __restrict__ s0g) {
    __shared__ float us[32][8][ID];       // 8 KB
    __shared__ float s0_blk[32][ODOC];    // 20 KB

    const int t = threadIdx.x;
    const int chunk = blockIdx.x % NCHUNK;
    const int bg    = blockIdx.x / NCHUNK;    // 0..7
    const int i0 = chunk * 8;

    for (int idx = t; idx < 32 * 8 * ID; idx += UK_THREADS) {
        int bb = idx >> 6, r = idx & 63, il = r >> 3, k = r & 7;
        us[bb][il][k] = u[((size_t)(bb * NBG + bg) * IC + (i0 + il)) * ID + k];
    }
    for (int idx = t; idx < 32 * ODOC; idx += UK_THREADS)
        ((float*)s0_blk)[idx] = 0.f;
    __syncthreads();

    const int il = t / 40;
    const int r  = t % 40;
    const int o  = r >> 2;
    const int dq = r & 3;
    const int i  = i0 + il;

    float w[4][ID];
    const float* wp = W + (((size_t)i * OC + o) * OD + dq * 4) * ID;
#pragma unroll
    for (int j = 0; j < 4; j++)
#pragma unroll
        for (int k = 0; k < ID; k++) w[j][k] = wp[j * ID + k];

    for (int bb = 0; bb < 32; ++bb) {
        const int b = bb * NBG + bg;
        float a0 = 0.f, a1 = 0.f, a2 = 0.f, a3 = 0.f;
#pragma unroll
        for (int k = 0; k < ID; k++) {
            float uu = us[bb][il][k];
            a0 += w[0][k] * uu;
            a1 += w[1][k] * uu;
            a2 += w[2][k] * uu;
            a3 += w[3][k] * uu;
        }
        uint2 pk = make_uint2(pack_bf16x2(a0, a1), pack_bf16x2(a2, a3));
        *(uint2*)(uhat + ((size_t)b * IC + i) * ODOC + o * OD + dq * 4) = pk;
        // s0 partial (f32, pre-rounding): LDS atomics, no barrier
        atomicAdd(&s0_blk[bb][o * OD + dq * 4 + 0], a0);
        atomicAdd(&s0_blk[bb][o * OD + dq * 4 + 1], a1);
        atomicAdd(&s0_blk[bb][o * OD + dq * 4 + 2], a2);
        atomicAdd(&s0_blk[bb][o * OD + dq * 4 + 3], a3);
    }
    __syncthreads();
    for (int idx = t; idx < 32 * ODOC; idx += UK_THREADS) {
        int bb = idx / ODOC, od = idx % ODOC;
        atomicAdd(&s0g[(size_t)(bb * NBG + bg) * ODOC + od], s0_blk[bb][od]);
    }
}

// Routing: one b per block, 1024 threads = 64 i-lanes x 16 slots (slot = o for
// slot<10). v0 comes from s0g (no pass-0 read). Two fused passes; logits in
// registers (Lreg[18], statically indexed via full unroll); no LDS/barriers in
// the step loops. 16 waves/CU for latency hiding.
__global__ __launch_bounds__(R_THREADS, 4) void routing_kernel(const u16* __restrict__ uhat,
                                                               const float* __restrict__ s0g,
                                                               float* __restrict__ out) {
    __shared__ float v_sh[ODOC];
    __shared__ float red[64 * ODOC];   // 40 KB

    const int t = threadIdx.x;
    const int b = blockIdx.x;
    const int il   = t >> 4;           // 0..63
    const int slot = t & 15;
    const bool act = slot < OC;

    if (t < ODOC) v_sh[t] = squash_val(s0g[(size_t)b * ODOC + t] * 0.1f);
    __syncthreads();

    const u16* ub = uhat + (size_t)b * IC * ODOC;

    float Lreg[R_STEPS];
#pragma unroll
    for (int j = 0; j < R_STEPS; ++j) Lreg[j] = 0.f;

#pragma unroll 1
    for (int pass = 1; pass <= 2; ++pass) {
        float vr[OD];
#pragma unroll
        for (int q = 0; q < 4; q++) {
            float4 vq = *(const float4*)&v_sh[slot * OD + q * 4];
            vr[q * 4 + 0] = vq.x; vr[q * 4 + 1] = vq.y;
            vr[q * 4 + 2] = vq.z; vr[q * 4 + 3] = vq.w;
        }
        float sp[OD];
#pragma unroll
        for (int d = 0; d < OD; ++d) sp[d] = 0.f;

#pragma unroll
        for (int step = 0; step < R_STEPS; ++step) {
            const int i = step * 64 + il;
            float uh[OD];
            float a = 0.f;
            if (act) {
                const uint4* p = (const uint4*)(ub + (size_t)i * ODOC + slot * OD);
                uint4 A = p[0], B = p[1];
                uh[0]  = bf_lo(A.x); uh[1]  = bf_hi(A.x);
                uh[2]  = bf_lo(A.y); uh[3]  = bf_hi(A.y);
                uh[4]  = bf_lo(A.z); uh[5]  = bf_hi(A.z);
                uh[6]  = bf_lo(A.w); uh[7]  = bf_hi(A.w);
                uh[8]  = bf_lo(B.x); uh[9]  = bf_hi(B.x);
                uh[10] = bf_lo(B.y); uh[11] = bf_hi(B.y);
                uh[12] = bf_lo(B.z); uh[13] = bf_hi(B.z);
                uh[14] = bf_lo(B.w); uh[15] = bf_hi(B.w);
#pragma unroll
                for (int d = 0; d < OD; d++) a += uh[d] * vr[d];
            }
            float Lv = -3.4e38f;
            if (act) { Lreg[step] += a; Lv = Lreg[step]; }
            float mx = grp16_max(Lv);
            float e  = act ? __expf(Lv - mx) : 0.f;
            float S  = grp16_sum(e);
            float c  = e / S;
            if (act) {
#pragma unroll
                for (int d = 0; d < OD; d++) sp[d] += c * uh[d];
            }
        }

        if (act) {
#pragma unroll
            for (int q = 0; q < 4; q++)
                *(float4*)&red[il * ODOC + slot * OD + q * 4] =
                    make_float4(sp[q * 4], sp[q * 4 + 1], sp[q * 4 + 2], sp[q * 4 + 3]);
        }
        __syncthreads();
        float sn = 0.f;
        if (t < ODOC) {
#pragma unroll 8
            for (int j = 0; j < 64; j++) sn += red[j * ODOC + t];
        }
        float vn = squash_val(sn);
        __syncthreads();
        if (pass == 1) {
            if (t < ODOC) v_sh[t] = vn;
            __syncthreads();
        } else {
            if (t < ODOC) out[(size_t)b * ODOC + t] = vn;
        }
    }
}

extern "C" void kernel_launch(void* const* d_in, const int* in_sizes, int n_in,
                              void* d_out, int out_size, void* d_ws, size_t ws_size,
                              hipStream_t stream) {
    const float* u = (const float*)d_in[0];
    const float* W = (const float*)d_in[1];
    float* out = (float*)d_out;

    const size_t uhat_bytes = (size_t)BB * IC * ODOC * sizeof(u16);   // 94,371,840
    u16*   uhat = (u16*)d_ws;
    float* s0g  = (float*)((char*)d_ws + uhat_bytes);

    hipMemsetAsync(s0g, 0, (size_t)BB * ODOC * sizeof(float), stream);
    hipLaunchKernelGGL(uhat_kernel, dim3(NCHUNK * NBG), dim3(UK_THREADS), 0, stream,
                       u, W, uhat, s0g);
    hipLaunchKernelGGL(routing_kernel, dim3(BB), dim3(R_THREADS), 0, stream,
                       uhat, s0g, out);
}

// Round 6
// 83.556 us; speedup vs baseline: 5.7932x; 3.8732x over previous
//
#include <hip/hip_runtime.h>
#include <math.h>

#define BB 256      // batch
#define IC 1152     // in caps
#define OC 10       // out caps
#define OD 16       // out dim
#define ID 8        // in dim
#define ODOC 160

#define NCHUNK 144      // i-chunks of 8
#define NBG 8           // b residue groups (32 b each)
#define UK_THREADS 320  // 8 il x 40 (o,dq)

#define R_THREADS 1024  // 64 il x 16 slot
#define R_IL 64
#define R_STEPS (IC/R_IL)   // 18

typedef unsigned int   u32;
typedef unsigned short u16;

__device__ __forceinline__ float grp16_sum(float x) {
#pragma unroll
    for (int m = 8; m >= 1; m >>= 1) x += __shfl_xor(x, m, 16);
    return x;
}
// squash over the 16-lane d-group
__device__ __forceinline__ float squash_val(float s) {
    float sq = grp16_sum(s * s);
    return s * (sq / ((1.f + sq) * (sqrtf(sq) + 1e-8f)));
}

__device__ __forceinline__ u32 bf16_rne(float f) {
    u32 x = __float_as_uint(f);
    return (x + 0x7FFFu + ((x >> 16) & 1u)) >> 16;
}
__device__ __forceinline__ u32 pack_bf16x2(float lo, float hi) {
    return bf16_rne(lo) | (bf16_rne(hi) << 16);
}
__device__ __forceinline__ float bf_lo(u32 v) { return __uint_as_float(v << 16); }
__device__ __forceinline__ float bf_hi(u32 v) { return __uint_as_float(v & 0xFFFF0000u); }

// Kernel 1 (round-3 verbatim — proven ~31 us at the write roofline).
// uhat[b,i,o,d] (bf16) = W[i,o,:,:] @ u[b,i,:]. PURE: no s0, no atomics, no
// extra LDS — the dense lockstep write window (all 1152 blocks write b in
// {8bb..8bb+7} at iter bb) is fragile to any per-iter latency variance.
__global__ __launch_bounds__(UK_THREADS) void uhat_kernel(const float* __restrict__ u,
                                                          const float* __restrict__ W,
                                                          u16* __restrict__ uhat) {
    __shared__ float us[32][8][ID];   // 8 KB

    const int t = threadIdx.x;
    const int chunk = blockIdx.x % NCHUNK;
    const int bg    = blockIdx.x / NCHUNK;    // 0..7
    const int i0 = chunk * 8;

    for (int idx = t; idx < 32 * 8 * ID; idx += UK_THREADS) {
        int bb = idx >> 6, r = idx & 63, il = r >> 3, k = r & 7;
        us[bb][il][k] = u[((size_t)(bb * NBG + bg) * IC + (i0 + il)) * ID + k];
    }
    __syncthreads();

    const int il = t / 40;
    const int r  = t % 40;
    const int o  = r >> 2;
    const int dq = r & 3;
    const int i  = i0 + il;

    float w[4][ID];
    const float* wp = W + (((size_t)i * OC + o) * OD + dq * 4) * ID;
#pragma unroll
    for (int j = 0; j < 4; j++)
#pragma unroll
        for (int k = 0; k < ID; k++) w[j][k] = wp[j * ID + k];

    for (int bb = 0; bb < 32; ++bb) {
        const int b = bb * NBG + bg;
        float a0 = 0.f, a1 = 0.f, a2 = 0.f, a3 = 0.f;
#pragma unroll
        for (int k = 0; k < ID; k++) {
            float uu = us[bb][il][k];
            a0 += w[0][k] * uu;
            a1 += w[1][k] * uu;
            a2 += w[2][k] * uu;
            a3 += w[3][k] * uu;
        }
        uint2 pk = make_uint2(pack_bf16x2(a0, a1), pack_bf16x2(a2, a3));
        *(uint2*)(uhat + ((size_t)b * IC + i) * ODOC + o * OD + dq * 4) = pk;
    }
}

// Routing: one b per block, 1024 threads = 64 i-lanes x 16 slots.
// Pass 0 (sum-only, v0): ALL 16 slots load — each 320 B row (20 uint4 chunks)
// split: slot s reads chunk s, and chunk 16+s if s<4. Zero idle load lanes.
// Passes 1-2: slots 0-9 own o-columns; logits in registers (Lreg[18], static
// index via full unroll); softmax WITHOUT max-subtraction (|logit| <~ 12,
// shift-invariant => identical result). No LDS/barriers in step loops.
__global__ __launch_bounds__(R_THREADS, 4) void routing_kernel(const u16* __restrict__ uhat,
                                                               float* __restrict__ out) {
    __shared__ float v_sh[ODOC];
    __shared__ float red[R_IL * ODOC];   // 40 KB

    const int t = threadIdx.x;
    const int b = blockIdx.x;
    const int il   = t >> 4;           // 0..63
    const int slot = t & 15;
    const bool act = slot < OC;

    const u16* ub = uhat + (size_t)b * IC * ODOC;

    // ---- pass 0: s0 = 0.1 * sum_i uh, all lanes loading ----
    {
        float spA[8], spB[8];
#pragma unroll
        for (int e = 0; e < 8; e++) { spA[e] = 0.f; spB[e] = 0.f; }
#pragma unroll
        for (int step = 0; step < R_STEPS; ++step) {
            const uint4* rp = (const uint4*)(ub + (size_t)(step * R_IL + il) * ODOC);
            uint4 A = rp[slot];
            spA[0] += bf_lo(A.x); spA[1] += bf_hi(A.x);
            spA[2] += bf_lo(A.y); spA[3] += bf_hi(A.y);
            spA[4] += bf_lo(A.z); spA[5] += bf_hi(A.z);
            spA[6] += bf_lo(A.w); spA[7] += bf_hi(A.w);
            if (slot < 4) {
                uint4 Bv = rp[16 + slot];
                spB[0] += bf_lo(Bv.x); spB[1] += bf_hi(Bv.x);
                spB[2] += bf_lo(Bv.y); spB[3] += bf_hi(Bv.y);
                spB[4] += bf_lo(Bv.z); spB[5] += bf_hi(Bv.z);
                spB[6] += bf_lo(Bv.w); spB[7] += bf_hi(Bv.w);
            }
        }
        *(float4*)&red[il * ODOC + slot * 8]     = make_float4(spA[0], spA[1], spA[2], spA[3]);
        *(float4*)&red[il * ODOC + slot * 8 + 4] = make_float4(spA[4], spA[5], spA[6], spA[7]);
        if (slot < 4) {
            *(float4*)&red[il * ODOC + 128 + slot * 8]     = make_float4(spB[0], spB[1], spB[2], spB[3]);
            *(float4*)&red[il * ODOC + 128 + slot * 8 + 4] = make_float4(spB[4], spB[5], spB[6], spB[7]);
        }
        __syncthreads();
        float s0 = 0.f;
        if (t < ODOC) {
#pragma unroll 8
            for (int j = 0; j < R_IL; j++) s0 += red[j * ODOC + t];
            s0 *= 0.1f;
        }
        float v0 = squash_val(s0);
        __syncthreads();          // red reads done before pass-1 overwrites
        if (t < ODOC) v_sh[t] = v0;
        __syncthreads();
    }

    float Lreg[R_STEPS];
#pragma unroll
    for (int j = 0; j < R_STEPS; ++j) Lreg[j] = 0.f;

    // ---- passes 1-2 ----
#pragma unroll 1
    for (int pass = 1; pass <= 2; ++pass) {
        float vr[OD];
#pragma unroll
        for (int q = 0; q < 4; q++) {
            float4 vq = *(const float4*)&v_sh[slot * OD + q * 4];
            vr[q * 4 + 0] = vq.x; vr[q * 4 + 1] = vq.y;
            vr[q * 4 + 2] = vq.z; vr[q * 4 + 3] = vq.w;
        }
        float sp[OD];
#pragma unroll
        for (int d = 0; d < OD; ++d) sp[d] = 0.f;

#pragma unroll
        for (int step = 0; step < R_STEPS; ++step) {
            const int i = step * R_IL + il;
            float uh[OD];
            float e = 0.f;
            if (act) {
                const uint4* p = (const uint4*)(ub + (size_t)i * ODOC + slot * OD);
                uint4 A = p[0], B = p[1];
                uh[0]  = bf_lo(A.x); uh[1]  = bf_hi(A.x);
                uh[2]  = bf_lo(A.y); uh[3]  = bf_hi(A.y);
                uh[4]  = bf_lo(A.z); uh[5]  = bf_hi(A.z);
                uh[6]  = bf_lo(A.w); uh[7]  = bf_hi(A.w);
                uh[8]  = bf_lo(B.x); uh[9]  = bf_hi(B.x);
                uh[10] = bf_lo(B.y); uh[11] = bf_hi(B.y);
                uh[12] = bf_lo(B.z); uh[13] = bf_hi(B.z);
                uh[14] = bf_lo(B.w); uh[15] = bf_hi(B.w);
                float a = 0.f;
#pragma unroll
                for (int d = 0; d < OD; d++) a += uh[d] * vr[d];
                Lreg[step] += a;
                e = __expf(Lreg[step]);   // no max-sub: |logit| <~ 12, safe
            }
            float S = grp16_sum(e);
            float c = e / S;
            if (act) {
#pragma unroll
                for (int d = 0; d < OD; d++) sp[d] += c * uh[d];
            }
        }

        if (act) {
#pragma unroll
            for (int q = 0; q < 4; q++)
                *(float4*)&red[il * ODOC + slot * OD + q * 4] =
                    make_float4(sp[q * 4], sp[q * 4 + 1], sp[q * 4 + 2], sp[q * 4 + 3]);
        }
        __syncthreads();
        float sn = 0.f;
        if (t < ODOC) {
#pragma unroll 8
            for (int j = 0; j < R_IL; j++) sn += red[j * ODOC + t];
        }
        float vn = squash_val(sn);
        __syncthreads();
        if (pass == 1) {
            if (t < ODOC) v_sh[t] = vn;
            __syncthreads();
        } else {
            if (t < ODOC) out[(size_t)b * ODOC + t] = vn;
        }
    }
}

extern "C" void kernel_launch(void* const* d_in, const int* in_sizes, int n_in,
                              void* d_out, int out_size, void* d_ws, size_t ws_size,
                              hipStream_t stream) {
    const float* u = (const float*)d_in[0];
    const float* W = (const float*)d_in[1];
    float* out = (float*)d_out;

    u16* uhat = (u16*)d_ws;   // 256*1152*160 bf16 = 94.4 MB

    hipLaunchKernelGGL(uhat_kernel, dim3(NCHUNK * NBG), dim3(UK_THREADS), 0, stream,
                       u, W, uhat);
    hipLaunchKernelGGL(routing_kernel, dim3(BB), dim3(R_THREADS), 0, stream,
                       uhat, out);
}